// Round 1
// baseline (8215.364 us; speedup 1.0000x reference)
//
#include <hip/hip_runtime.h>
#include <hip/hip_bf16.h>

// GRU: B=128, T=1024, D_IN=512, H=1024. Output = final hidden state [128,1024] fp32.
//
// Round 5 (on top of round-4 group-local-barrier structure):
//  - x pre-packed to bf16 once (pack_x), guarded by ws_size; halves per-step x
//    traffic, removes per-step pack VALU, and 128MB bf16 x is L3-resident.
//  - phase 2 dedup: each wave owns a unique K-eighth of rh and computes BOTH
//    column halves (same weight regs). rh L3 reads 64KB -> 32KB per WG/step.
//  - x@W_z / x@W_r partials for t+1 computed inside the barrier-2 poll window
//    (CU otherwise idle); stage A rebalanced to an even 16/16 h-K split and no
//    longer touches xsh at all.

#define BB   128
#define TT   1024
#define DIN  512
#define HD   1024

typedef short short8 __attribute__((ext_vector_type(8)));
typedef float f32x4 __attribute__((ext_vector_type(4)));
typedef unsigned long long ull;

// ws layout (bytes)
#define FLAGS_OFF 0                        // 8 groups * 32 flags * 4B = 1024
#define WT_OFF    16384
#define RT_OFF    (WT_OFF + 3*HD*DIN*2)
#define HBF_OFF   (RT_OFF + 3*HD*HD*2)
#define RH_OFF    (HBF_OFF + BB*HD*2)
#define XBF_OFF   (RH_OFF + BB*HD*2)
#define XBF_BYTES ((size_t)BB*TT*DIN*2)

__device__ __forceinline__ unsigned short f2bf(float f) {
    unsigned u = __builtin_bit_cast(unsigned, f);
    u = (u + 0x7FFFu + ((u >> 16) & 1u)) >> 16;   // RNE
    return (unsigned short)u;
}

__device__ __forceinline__ ull pack4(const float* p) {
    return (ull)f2bf(p[0]) | ((ull)f2bf(p[1]) << 16) |
           ((ull)f2bf(p[2]) << 32) | ((ull)f2bf(p[3]) << 48);
}

__device__ __forceinline__ ull pack4v(float4 v) {
    return (ull)f2bf(v.x) | ((ull)f2bf(v.y) << 16) |
           ((ull)f2bf(v.z) << 32) | ((ull)f2bf(v.w) << 48);
}

__device__ __forceinline__ short8 ld8(const unsigned short* p) {
    return *(const short8*)p;
}

__device__ __forceinline__ ull ald(const ull* p) {
    return __hip_atomic_load(p, __ATOMIC_RELAXED, __HIP_MEMORY_SCOPE_AGENT);
}
__device__ __forceinline__ void ast(ull* p, ull v) {
    __hip_atomic_store(p, v, __ATOMIC_RELAXED, __HIP_MEMORY_SCOPE_AGENT);
}

#define MFMA(A, B, C) __builtin_amdgcn_mfma_f32_16x16x32_bf16((A), (B), (C), 0, 0, 0)

// ---- phase 0a: transpose + bf16-convert weights ----------------------------
__global__ void pack_weights(const float* __restrict__ w0, const float* __restrict__ w1,
                             const float* __restrict__ w2, const float* __restrict__ r0,
                             const float* __restrict__ r1, const float* __restrict__ r2,
                             unsigned short* __restrict__ wt, unsigned short* __restrict__ rt) {
    int z = blockIdx.z;
    int K = (z < 3) ? DIN : HD;
    int kb = blockIdx.x * 32;
    if (kb >= K) return;
    int nb = blockIdx.y * 32;
    const float* src = (z == 0) ? w0 : (z == 1) ? w1 : (z == 2) ? w2
                     : (z == 3) ? r0 : (z == 4) ? r1 : r2;
    unsigned short* dst = (z < 3) ? (wt + (size_t)z * HD * DIN)
                                  : (rt + (size_t)(z - 3) * HD * HD);
    __shared__ float tile[32][33];
    int tx = threadIdx.x & 31, ty = threadIdx.x >> 5;
    for (int i = ty; i < 32; i += 8)
        tile[i][tx] = src[(size_t)(kb + i) * HD + nb + tx];
    __syncthreads();
    for (int i = ty; i < 32; i += 8)
        dst[(size_t)(nb + i) * K + kb + tx] = f2bf(tile[tx][i]);
}

// ---- phase 0b: bf16-convert x ----------------------------------------------
__global__ void pack_x(const float* __restrict__ x, unsigned short* __restrict__ xbf,
                       long long n4) {
    long long i = (long long)blockIdx.x * blockDim.x + threadIdx.x;
    long long stride = (long long)gridDim.x * blockDim.x;
    const float4* xv = (const float4*)x;
    ull* o = (ull*)xbf;
    for (; i < n4; i += stride) o[i] = pack4v(xv[i]);
}

// ---- persistent GRU kernel -------------------------------------------------
__launch_bounds__(512, 2)
__global__ void gru_persistent(const float* __restrict__ x,
                               const unsigned short* __restrict__ xbf,  // may be null
                               const float* __restrict__ Bz, const float* __restrict__ Br,
                               const float* __restrict__ Bh,
                               const unsigned short* __restrict__ WT,
                               const unsigned short* __restrict__ RT,
                               unsigned short* __restrict__ hbf,
                               unsigned short* __restrict__ rhbf,
                               unsigned* __restrict__ flags,
                               float* __restrict__ out) {
    const int g = blockIdx.x;
    const int group  = g & 7;            // likely XCD id (blockIdx % 8)
    const int member = g >> 3;           // 0..31 within group
    const int rowbase = group * 16;
    const int colbase = member * 32;
    const int tid  = threadIdx.x;
    const int w    = tid >> 6;
    const int lane = tid & 63;
    const int frow = lane & 15;
    const int fquad = lane >> 4;
    const int k0 = fquad * 8;

    // stage A roles: (gA: z/r, cA: col half, hA: K half)
    const int gA = (w >> 2) & 1;
    const int cA = (w >> 1) & 1;
    const int hA = w & 1;
    // phase-1 x@W_h roles (w < 4)
    const int cB = w & 1;
    const int xh = (w >> 1) & 1;

    __shared__ unsigned short xsh[16][520];
    __shared__ unsigned short hsh[16][1032];
    __shared__ float zbuf[16][36];
    __shared__ float rtmp[16][36];
    __shared__ float hstate[16][36];
    __shared__ float redA[2][2][4][64];
    __shared__ float redB[2][10][4][64];  // [col-half][0..7: rh K-eighths, 8..9: x halves]

    unsigned* gflags = flags + group * 32;   // 128B: 2 cache lines

    if (tid < 128) {
        int row = tid >> 3, c4 = tid & 7;
        *(float4*)&hstate[row][c4 * 4] = make_float4(0.f, 0.f, 0.f, 0.f);
    }

    // ---- weight preload into registers (unified VGPR/AGPR file) -----------
    short8 wAx[8], wAh[16], wB0[4], wB1[4], wBx[8];
    {
        const unsigned short* wcolA = WT + ((size_t)gA * HD + colbase + cA * 16 + frow) * DIN;
        const unsigned short* rcolA = RT + ((size_t)gA * HD + colbase + cA * 16 + frow) * HD;
        #pragma unroll
        for (int i = 0; i < 8; ++i)  wAx[i] = ld8(wcolA + (hA * 8 + i) * 32 + k0);
        #pragma unroll
        for (int i = 0; i < 16; ++i) wAh[i] = ld8(rcolA + (hA * 16 + i) * 32 + k0);

        const unsigned short* rcolB0 = RT + ((size_t)2 * HD + colbase + frow) * HD;
        const unsigned short* rcolB1 = RT + ((size_t)2 * HD + colbase + 16 + frow) * HD;
        #pragma unroll
        for (int i = 0; i < 4; ++i) wB0[i] = ld8(rcolB0 + (w * 4 + i) * 32 + k0);
        #pragma unroll
        for (int i = 0; i < 4; ++i) wB1[i] = ld8(rcolB1 + (w * 4 + i) * 32 + k0);

        if (w < 4) {
            const unsigned short* wcolB = WT + ((size_t)2 * HD + colbase + cB * 16 + frow) * DIN;
            #pragma unroll
            for (int i = 0; i < 8; ++i) wBx[i] = ld8(wcolB + (xh * 8 + i) * 32 + k0);
        }
    }
    const float bvA = (gA == 0 ? Bz : Br)[colbase + cA * 16 + frow];
    const float bvB = Bh[colbase + (w & 1) * 16 + frow];

    const ull* hbf_u = (const ull*)hbf;
    const ull* rh_u  = (const ull*)rhbf;

#define STAGE_X(tt) do {                                                              \
        if (xbf) {                                                                    \
            const ull* xr = (const ull*)xbf;                                          \
            for (int i = tid; i < 2048; i += 512) {                                   \
                int row = i >> 7, c4 = i & 127;                                       \
                *(ull*)&xsh[row][c4 * 4] =                                            \
                    xr[((size_t)(rowbase + row) * TT + (tt)) * (DIN / 4) + c4];       \
            }                                                                         \
        } else {                                                                      \
            for (int i = tid; i < 2048; i += 512) {                                   \
                int row = i >> 7, c4 = i & 127;                                       \
                *(ull*)&xsh[row][c4 * 4] = pack4v(                                    \
                    ((const float4*)(x + ((size_t)(rowbase + row) * TT + (tt)) * DIN))[c4]); \
            }                                                                         \
        }                                                                             \
    } while (0)

    // x@W_{z,r} partials, loop-carried (computed for t+1 during barrier-2 poll)
    f32x4 xa0, xa1;
#define COMPUTE_XA() do {                                                             \
        f32x4 t0 = {0.f,0.f,0.f,0.f}, t1 = {0.f,0.f,0.f,0.f};                         \
        _Pragma("unroll")                                                             \
        for (int i = 0; i < 8; i += 2) {                                              \
            t0 = MFMA(ld8(&xsh[frow][(hA * 8 + i) * 32 + k0]), wAx[i], t0);           \
            t1 = MFMA(ld8(&xsh[frow][(hA * 8 + i + 1) * 32 + k0]), wAx[i + 1], t1);   \
        }                                                                             \
        xa0 = t0; xa1 = t1;                                                           \
    } while (0)

    // stage x[0] + its z/r partials
    STAGE_X(0);
    __syncthreads();
    COMPUTE_XA();

    unsigned phase = 0;

    for (int t = 0; t < TT; ++t) {
        // ---- phase 1: h loads into regs; x@W_h hidden under their latency --
        ull hreg[8];
        {
            const int c8 = tid & 255;
            const int r0r = tid >> 8;
            #pragma unroll
            for (int j = 0; j < 8; ++j)
                hreg[j] = ald(hbf_u + (size_t)(rowbase + r0r + 2 * j) * 256 + c8);
        }
        if (w < 4) {                      // x @ W_h partials (xsh only)
            f32x4 b0 = {0.f,0.f,0.f,0.f}, b1 = {0.f,0.f,0.f,0.f};
            #pragma unroll
            for (int i = 0; i < 8; i += 2) {
                b0 = MFMA(ld8(&xsh[frow][(xh * 8 + i) * 32 + k0]), wBx[i], b0);
                b1 = MFMA(ld8(&xsh[frow][(xh * 8 + i + 1) * 32 + k0]), wBx[i + 1], b1);
            }
            #pragma unroll
            for (int r4 = 0; r4 < 4; ++r4) redB[cB][8 + xh][r4][lane] = b0[r4] + b1[r4];
        }
        {
            const int c8 = tid & 255;
            const int r0r = tid >> 8;
            #pragma unroll
            for (int j = 0; j < 8; ++j)
                *(ull*)&hsh[r0r + 2 * j][c8 * 4] = hreg[j];
        }
        __syncthreads();

        // ---- stage A: z, r (h-K split evenly 16/16; x part precomputed) ----
        {
            f32x4 a0 = xa0, a1 = xa1;
            #pragma unroll
            for (int i = 0; i < 16; i += 2) {
                a0 = MFMA(ld8(&hsh[frow][(hA * 16 + i) * 32 + k0]), wAh[i], a0);
                a1 = MFMA(ld8(&hsh[frow][(hA * 16 + i + 1) * 32 + k0]), wAh[i + 1], a1);
            }
            if (hA == 1) {
                #pragma unroll
                for (int r4 = 0; r4 < 4; ++r4)
                    redA[gA][cA][r4][lane] = a0[r4] + a1[r4];
            }
            __syncthreads();
            if (hA == 0) {
                const int c = cA * 16 + frow;
                #pragma unroll
                for (int r4 = 0; r4 < 4; ++r4) {
                    int row = fquad * 4 + r4;
                    float pre = a0[r4] + a1[r4] + redA[gA][cA][r4][lane] + bvA;
                    float sg = 1.f / (1.f + __expf(-pre));
                    if (gA == 0) zbuf[row][c] = sg;
                    else         rtmp[row][c] = sg * hstate[row][c];
                }
            }
        }
        __syncthreads();
        if (tid < 128) {                               // publish r*h
            int row = tid >> 3, c4 = tid & 7;
            ast((ull*)rhbf + (size_t)(rowbase + row) * 256 + (colbase >> 2) + c4,
                pack4(&rtmp[row][c4 * 4]));
        }
        __syncthreads();                               // drain publishes
        ++phase;
        if (tid == 0)
            __hip_atomic_store(gflags + member, phase,
                               __ATOMIC_RELAXED, __HIP_MEMORY_SCOPE_AGENT);
        if (t + 1 < TT) {                              // x[t+1]: overlaps poll
            STAGE_X(t + 1);
        }
        if (tid < 32) {
            while (__hip_atomic_load(gflags + tid, __ATOMIC_RELAXED,
                                     __HIP_MEMORY_SCOPE_AGENT) < phase)
                __builtin_amdgcn_s_sleep(1);
        }
        __syncthreads();

        // ---- phase 2: (r*h)@R_h — each wave a unique K-eighth, both halves -
        {
            f32x4 b0 = {0.f,0.f,0.f,0.f}, b1 = {0.f,0.f,0.f,0.f};
            const ull* rrow = rh_u + (size_t)(rowbase + frow) * 256 + w * 32 + fquad * 2;
            union { ull u[2]; short8 s; } fr[4];
            #pragma unroll
            for (int i = 0; i < 4; ++i) {
                fr[i].u[0] = ald(rrow + i * 8);
                fr[i].u[1] = ald(rrow + i * 8 + 1);
            }
            #pragma unroll
            for (int i = 0; i < 4; ++i) {
                b0 = MFMA(fr[i].s, wB0[i], b0);
                b1 = MFMA(fr[i].s, wB1[i], b1);
            }
            #pragma unroll
            for (int r4 = 0; r4 < 4; ++r4) {
                redB[0][w][r4][lane] = b0[r4];
                redB[1][w][r4][lane] = b1[r4];
            }
            __syncthreads();
            if (w < 2) {
                const int c = w * 16 + frow;
                #pragma unroll
                for (int r4 = 0; r4 < 4; ++r4) {
                    int row = fquad * 4 + r4;
                    float pre = bvB;
                    #pragma unroll
                    for (int s = 0; s < 10; ++s) pre += redB[w][s][r4][lane];
                    float e = __expf(2.f * pre);       // tanh = 1 - 2/(e+1)
                    float ht = 1.f - 2.f / (e + 1.f);
                    float zv = zbuf[row][c];
                    float ho = hstate[row][c];
                    hstate[row][c] = ho + zv * (ht - ho);
                }
            }
        }
        __syncthreads();

        if (t + 1 < TT) {
            if (tid < 128) {                           // publish h
                int row = tid >> 3, c4 = tid & 7;
                ast((ull*)hbf + (size_t)(rowbase + row) * 256 + (colbase >> 2) + c4,
                    pack4(&hstate[row][c4 * 4]));
            }
            __syncthreads();                           // drain publishes
            ++phase;
            if (tid == 0)
                __hip_atomic_store(gflags + member, phase,
                                   __ATOMIC_RELAXED, __HIP_MEMORY_SCOPE_AGENT);
            // x@W_{z,r} partials for t+1: overlaps the barrier-2 poll window
            COMPUTE_XA();
            if (tid < 32) {
                while (__hip_atomic_load(gflags + tid, __ATOMIC_RELAXED,
                                         __HIP_MEMORY_SCOPE_AGENT) < phase)
                    __builtin_amdgcn_s_sleep(1);
            }
            __syncthreads();
        }
    }

    if (tid < 128) {                                   // final output, fp32
        int row = tid >> 3, c4 = tid & 7;
        *(float4*)(out + (size_t)(rowbase + row) * HD + colbase + c4 * 4) =
            *(float4*)&hstate[row][c4 * 4];
    }
}

extern "C" void kernel_launch(void* const* d_in, const int* in_sizes, int n_in,
                              void* d_out, int out_size, void* d_ws, size_t ws_size,
                              hipStream_t stream) {
    const float* x  = (const float*)d_in[0];
    const float* Wz = (const float*)d_in[1];
    const float* Wr = (const float*)d_in[2];
    const float* Wh = (const float*)d_in[3];
    const float* Rz = (const float*)d_in[4];
    const float* Rr = (const float*)d_in[5];
    const float* Rh = (const float*)d_in[6];
    const float* Bz = (const float*)d_in[7];
    const float* Br = (const float*)d_in[8];
    const float* Bh = (const float*)d_in[9];

    char* ws = (char*)d_ws;
    unsigned*       flags = (unsigned*)(ws + FLAGS_OFF);
    unsigned short* WT    = (unsigned short*)(ws + WT_OFF);
    unsigned short* RT    = (unsigned short*)(ws + RT_OFF);
    unsigned short* hbf   = (unsigned short*)(ws + HBF_OFF);
    unsigned short* rhbf  = (unsigned short*)(ws + RH_OFF);

    const bool use_xbf = ws_size >= (size_t)XBF_OFF + XBF_BYTES;
    unsigned short* XBF = use_xbf ? (unsigned short*)(ws + XBF_OFF) : nullptr;

    hipMemsetAsync(ws + FLAGS_OFF, 0, 1024, stream);         // flags = 0
    hipMemsetAsync(ws + HBF_OFF, 0, BB * HD * 2, stream);    // h0 = 0

    dim3 pgrid(HD / 32, HD / 32, 6);
    pack_weights<<<pgrid, 256, 0, stream>>>(Wz, Wr, Wh, Rz, Rr, Rh, WT, RT);
    if (use_xbf)
        pack_x<<<2048, 256, 0, stream>>>(x, XBF,
                                         (long long)((size_t)BB * TT * DIN / 4));

    gru_persistent<<<256, 512, 0, stream>>>(x, XBF, Bz, Br, Bh, WT, RT, hbf, rhbf,
                                            flags, (float*)d_out);
}

// Round 2
// 8019.433 us; speedup vs baseline: 1.0244x; 1.0244x over previous
//
#include <hip/hip_runtime.h>
#include <hip/hip_bf16.h>

// GRU: B=128, T=1024, D_IN=512, H=1024. Output = final hidden state [128,1024] fp32.
//
// Round 6 (on top of round-5):
//  - Per-source polling. Flags are monotone counters (rh[t] -> 2t+1, h[t] -> 2t+2).
//    Phase-1: each thread polls ONLY the member owning its h column (c8>>3), then
//    issues its 8 loads immediately. Phase-2: each wave polls ONLY the 4 members
//    (4w..4w+3) whose rh chunk it consumes. The dedicated 32-flag poll loops and
//    their two __syncthreads are gone; the end-of-step poll folds into the next
//    step's phase-1. WAR safety preserved by collective coverage: all 512 threads
//    together observe all 32 flags >= 2t before rh[t] publish; all 8 waves
//    together observe >= 2t+1 before h[t] publish (flags are monotone).
//  - Numerics identical to round 5 (same op order).

#define BB   128
#define TT   1024
#define DIN  512
#define HD   1024

typedef short short8 __attribute__((ext_vector_type(8)));
typedef float f32x4 __attribute__((ext_vector_type(4)));
typedef unsigned long long ull;

// ws layout (bytes)
#define FLAGS_OFF 0                        // 8 groups * 32 flags * 4B = 1024
#define WT_OFF    16384
#define RT_OFF    (WT_OFF + 3*HD*DIN*2)
#define HBF_OFF   (RT_OFF + 3*HD*HD*2)
#define RH_OFF    (HBF_OFF + BB*HD*2)
#define XBF_OFF   (RH_OFF + BB*HD*2)
#define XBF_BYTES ((size_t)BB*TT*DIN*2)

__device__ __forceinline__ unsigned short f2bf(float f) {
    unsigned u = __builtin_bit_cast(unsigned, f);
    u = (u + 0x7FFFu + ((u >> 16) & 1u)) >> 16;   // RNE
    return (unsigned short)u;
}

__device__ __forceinline__ ull pack4(const float* p) {
    return (ull)f2bf(p[0]) | ((ull)f2bf(p[1]) << 16) |
           ((ull)f2bf(p[2]) << 32) | ((ull)f2bf(p[3]) << 48);
}

__device__ __forceinline__ ull pack4v(float4 v) {
    return (ull)f2bf(v.x) | ((ull)f2bf(v.y) << 16) |
           ((ull)f2bf(v.z) << 32) | ((ull)f2bf(v.w) << 48);
}

__device__ __forceinline__ short8 ld8(const unsigned short* p) {
    return *(const short8*)p;
}

__device__ __forceinline__ ull ald(const ull* p) {
    return __hip_atomic_load(p, __ATOMIC_RELAXED, __HIP_MEMORY_SCOPE_AGENT);
}
__device__ __forceinline__ void ast(ull* p, ull v) {
    __hip_atomic_store(p, v, __ATOMIC_RELAXED, __HIP_MEMORY_SCOPE_AGENT);
}
__device__ __forceinline__ unsigned aldf(const unsigned* p) {
    return __hip_atomic_load(p, __ATOMIC_RELAXED, __HIP_MEMORY_SCOPE_AGENT);
}

#define MFMA(A, B, C) __builtin_amdgcn_mfma_f32_16x16x32_bf16((A), (B), (C), 0, 0, 0)

// ---- phase 0a: transpose + bf16-convert weights ----------------------------
__global__ void pack_weights(const float* __restrict__ w0, const float* __restrict__ w1,
                             const float* __restrict__ w2, const float* __restrict__ r0,
                             const float* __restrict__ r1, const float* __restrict__ r2,
                             unsigned short* __restrict__ wt, unsigned short* __restrict__ rt) {
    int z = blockIdx.z;
    int K = (z < 3) ? DIN : HD;
    int kb = blockIdx.x * 32;
    if (kb >= K) return;
    int nb = blockIdx.y * 32;
    const float* src = (z == 0) ? w0 : (z == 1) ? w1 : (z == 2) ? w2
                     : (z == 3) ? r0 : (z == 4) ? r1 : r2;
    unsigned short* dst = (z < 3) ? (wt + (size_t)z * HD * DIN)
                                  : (rt + (size_t)(z - 3) * HD * HD);
    __shared__ float tile[32][33];
    int tx = threadIdx.x & 31, ty = threadIdx.x >> 5;
    for (int i = ty; i < 32; i += 8)
        tile[i][tx] = src[(size_t)(kb + i) * HD + nb + tx];
    __syncthreads();
    for (int i = ty; i < 32; i += 8)
        dst[(size_t)(nb + i) * K + kb + tx] = f2bf(tile[tx][i]);
}

// ---- phase 0b: bf16-convert x ----------------------------------------------
__global__ void pack_x(const float* __restrict__ x, unsigned short* __restrict__ xbf,
                       long long n4) {
    long long i = (long long)blockIdx.x * blockDim.x + threadIdx.x;
    long long stride = (long long)gridDim.x * blockDim.x;
    const float4* xv = (const float4*)x;
    ull* o = (ull*)xbf;
    for (; i < n4; i += stride) o[i] = pack4v(xv[i]);
}

// ---- persistent GRU kernel -------------------------------------------------
__launch_bounds__(512, 2)
__global__ void gru_persistent(const float* __restrict__ x,
                               const unsigned short* __restrict__ xbf,  // may be null
                               const float* __restrict__ Bz, const float* __restrict__ Br,
                               const float* __restrict__ Bh,
                               const unsigned short* __restrict__ WT,
                               const unsigned short* __restrict__ RT,
                               unsigned short* __restrict__ hbf,
                               unsigned short* __restrict__ rhbf,
                               unsigned* __restrict__ flags,
                               float* __restrict__ out) {
    const int g = blockIdx.x;
    const int group  = g & 7;            // likely XCD id (blockIdx % 8)
    const int member = g >> 3;           // 0..31 within group
    const int rowbase = group * 16;
    const int colbase = member * 32;
    const int tid  = threadIdx.x;
    const int w    = tid >> 6;
    const int lane = tid & 63;
    const int frow = lane & 15;
    const int fquad = lane >> 4;
    const int k0 = fquad * 8;

    // stage A roles: (gA: z/r, cA: col half, hA: K half)
    const int gA = (w >> 2) & 1;
    const int cA = (w >> 1) & 1;
    const int hA = w & 1;
    // phase-1 x@W_h roles (w < 4)
    const int cB = w & 1;
    const int xh = (w >> 1) & 1;

    __shared__ unsigned short xsh[16][520];
    __shared__ unsigned short hsh[16][1032];
    __shared__ float zbuf[16][36];
    __shared__ float rtmp[16][36];
    __shared__ float hstate[16][36];
    __shared__ float redA[2][2][4][64];
    __shared__ float redB[2][10][4][64];  // [col-half][0..7: rh K-eighths, 8..9: x halves]

    unsigned* gflags = flags + group * 32;   // 128B: 2 cache lines

    if (tid < 128) {
        int row = tid >> 3, c4 = tid & 7;
        *(float4*)&hstate[row][c4 * 4] = make_float4(0.f, 0.f, 0.f, 0.f);
    }

    // ---- weight preload into registers (unified VGPR/AGPR file) -----------
    short8 wAx[8], wAh[16], wB0[4], wB1[4], wBx[8];
    {
        const unsigned short* wcolA = WT + ((size_t)gA * HD + colbase + cA * 16 + frow) * DIN;
        const unsigned short* rcolA = RT + ((size_t)gA * HD + colbase + cA * 16 + frow) * HD;
        #pragma unroll
        for (int i = 0; i < 8; ++i)  wAx[i] = ld8(wcolA + (hA * 8 + i) * 32 + k0);
        #pragma unroll
        for (int i = 0; i < 16; ++i) wAh[i] = ld8(rcolA + (hA * 16 + i) * 32 + k0);

        const unsigned short* rcolB0 = RT + ((size_t)2 * HD + colbase + frow) * HD;
        const unsigned short* rcolB1 = RT + ((size_t)2 * HD + colbase + 16 + frow) * HD;
        #pragma unroll
        for (int i = 0; i < 4; ++i) wB0[i] = ld8(rcolB0 + (w * 4 + i) * 32 + k0);
        #pragma unroll
        for (int i = 0; i < 4; ++i) wB1[i] = ld8(rcolB1 + (w * 4 + i) * 32 + k0);

        if (w < 4) {
            const unsigned short* wcolB = WT + ((size_t)2 * HD + colbase + cB * 16 + frow) * DIN;
            #pragma unroll
            for (int i = 0; i < 8; ++i) wBx[i] = ld8(wcolB + (xh * 8 + i) * 32 + k0);
        }
    }
    const float bvA = (gA == 0 ? Bz : Br)[colbase + cA * 16 + frow];
    const float bvB = Bh[colbase + (w & 1) * 16 + frow];

    const ull* hbf_u = (const ull*)hbf;
    const ull* rh_u  = (const ull*)rhbf;

#define STAGE_X(tt) do {                                                              \
        if (xbf) {                                                                    \
            const ull* xr = (const ull*)xbf;                                          \
            for (int i = tid; i < 2048; i += 512) {                                   \
                int row = i >> 7, c4 = i & 127;                                       \
                *(ull*)&xsh[row][c4 * 4] =                                            \
                    xr[((size_t)(rowbase + row) * TT + (tt)) * (DIN / 4) + c4];       \
            }                                                                         \
        } else {                                                                      \
            for (int i = tid; i < 2048; i += 512) {                                   \
                int row = i >> 7, c4 = i & 127;                                       \
                *(ull*)&xsh[row][c4 * 4] = pack4v(                                    \
                    ((const float4*)(x + ((size_t)(rowbase + row) * TT + (tt)) * DIN))[c4]); \
            }                                                                         \
        }                                                                             \
    } while (0)

    // x@W_{z,r} partials, loop-carried (computed for t+1 after the h publish)
    f32x4 xa0, xa1;
#define COMPUTE_XA() do {                                                             \
        f32x4 t0 = {0.f,0.f,0.f,0.f}, t1 = {0.f,0.f,0.f,0.f};                         \
        _Pragma("unroll")                                                             \
        for (int i = 0; i < 8; i += 2) {                                              \
            t0 = MFMA(ld8(&xsh[frow][(hA * 8 + i) * 32 + k0]), wAx[i], t0);           \
            t1 = MFMA(ld8(&xsh[frow][(hA * 8 + i + 1) * 32 + k0]), wAx[i + 1], t1);   \
        }                                                                             \
        xa0 = t0; xa1 = t1;                                                           \
    } while (0)

    // stage x[0] + its z/r partials
    STAGE_X(0);
    __syncthreads();
    COMPUTE_XA();

    const int c8  = tid & 255;           // h-exchange column (ull index)
    const int r0r = tid >> 8;
    const unsigned* myflag1 = gflags + (c8 >> 3);   // phase-1: member owning my column

    for (int t = 0; t < TT; ++t) {
        // ---- phase 1: per-thread poll for h[t-1], then load immediately ----
        if (t) {
            const unsigned need = 2u * (unsigned)t;
            while (aldf(myflag1) < need) __builtin_amdgcn_s_sleep(1);
            asm volatile("" ::: "memory");           // keep loads after the poll
        }
        ull hreg[8];
        #pragma unroll
        for (int j = 0; j < 8; ++j)
            hreg[j] = ald(hbf_u + (size_t)(rowbase + r0r + 2 * j) * 256 + c8);
        if (w < 4) {                      // x @ W_h partials (xsh only)
            f32x4 b0 = {0.f,0.f,0.f,0.f}, b1 = {0.f,0.f,0.f,0.f};
            #pragma unroll
            for (int i = 0; i < 8; i += 2) {
                b0 = MFMA(ld8(&xsh[frow][(xh * 8 + i) * 32 + k0]), wBx[i], b0);
                b1 = MFMA(ld8(&xsh[frow][(xh * 8 + i + 1) * 32 + k0]), wBx[i + 1], b1);
            }
            #pragma unroll
            for (int r4 = 0; r4 < 4; ++r4) redB[cB][8 + xh][r4][lane] = b0[r4] + b1[r4];
        }
        #pragma unroll
        for (int j = 0; j < 8; ++j)
            *(ull*)&hsh[r0r + 2 * j][c8 * 4] = hreg[j];
        __syncthreads();

        // ---- stage A: z, r (h-K split evenly 16/16; x part precomputed) ----
        {
            f32x4 a0 = xa0, a1 = xa1;
            #pragma unroll
            for (int i = 0; i < 16; i += 2) {
                a0 = MFMA(ld8(&hsh[frow][(hA * 16 + i) * 32 + k0]), wAh[i], a0);
                a1 = MFMA(ld8(&hsh[frow][(hA * 16 + i + 1) * 32 + k0]), wAh[i + 1], a1);
            }
            if (hA == 1) {
                #pragma unroll
                for (int r4 = 0; r4 < 4; ++r4)
                    redA[gA][cA][r4][lane] = a0[r4] + a1[r4];
            }
            __syncthreads();
            if (hA == 0) {
                const int c = cA * 16 + frow;
                #pragma unroll
                for (int r4 = 0; r4 < 4; ++r4) {
                    int row = fquad * 4 + r4;
                    float pre = a0[r4] + a1[r4] + redA[gA][cA][r4][lane] + bvA;
                    float sg = 1.f / (1.f + __expf(-pre));
                    if (gA == 0) zbuf[row][c] = sg;
                    else         rtmp[row][c] = sg * hstate[row][c];
                }
            }
        }
        __syncthreads();

        // ---- publish r*h; flag = 2t+1 -------------------------------------
        if (tid < 128) {
            int row = tid >> 3, c4 = tid & 7;
            ast((ull*)rhbf + (size_t)(rowbase + row) * 256 + (colbase >> 2) + c4,
                pack4(&rtmp[row][c4 * 4]));
        }
        __syncthreads();                               // drain publishes
        if (tid == 0)
            __hip_atomic_store(gflags + member, 2u * (unsigned)t + 1u,
                               __ATOMIC_RELAXED, __HIP_MEMORY_SCOPE_AGENT);
        if (t + 1 < TT) {                              // x[t+1]: overlaps peers' publishes
            STAGE_X(t + 1);
        }

        // ---- phase 2: per-wave poll of the 4 members this wave consumes ----
        {
            if (lane < 4) {
                const unsigned need = 2u * (unsigned)t + 1u;
                const unsigned* fp = gflags + 4 * w + lane;
                while (aldf(fp) < need) __builtin_amdgcn_s_sleep(1);
            }
            asm volatile("" ::: "memory");             // keep loads after the poll

            f32x4 b0 = {0.f,0.f,0.f,0.f}, b1 = {0.f,0.f,0.f,0.f};
            const ull* rrow = rh_u + (size_t)(rowbase + frow) * 256 + w * 32 + fquad * 2;
            union { ull u[2]; short8 s; } fr[4];
            #pragma unroll
            for (int i = 0; i < 4; ++i) {
                fr[i].u[0] = ald(rrow + i * 8);
                fr[i].u[1] = ald(rrow + i * 8 + 1);
            }
            #pragma unroll
            for (int i = 0; i < 4; ++i) {
                b0 = MFMA(fr[i].s, wB0[i], b0);
                b1 = MFMA(fr[i].s, wB1[i], b1);
            }
            #pragma unroll
            for (int r4 = 0; r4 < 4; ++r4) {
                redB[0][w][r4][lane] = b0[r4];
                redB[1][w][r4][lane] = b1[r4];
            }
            __syncthreads();
            if (w < 2) {
                const int c = w * 16 + frow;
                #pragma unroll
                for (int r4 = 0; r4 < 4; ++r4) {
                    int row = fquad * 4 + r4;
                    float pre = bvB;
                    #pragma unroll
                    for (int s = 0; s < 10; ++s) pre += redB[w][s][r4][lane];
                    float e = __expf(2.f * pre);       // tanh = 1 - 2/(e+1)
                    float ht = 1.f - 2.f / (e + 1.f);
                    float zv = zbuf[row][c];
                    float ho = hstate[row][c];
                    hstate[row][c] = ho + zv * (ht - ho);
                }
            }
        }
        __syncthreads();

        // ---- publish h; flag = 2t+2 (poll folded into next phase 1) --------
        if (t + 1 < TT) {
            if (tid < 128) {
                int row = tid >> 3, c4 = tid & 7;
                ast((ull*)hbf + (size_t)(rowbase + row) * 256 + (colbase >> 2) + c4,
                    pack4(&hstate[row][c4 * 4]));
            }
            __syncthreads();                           // drain publishes
            if (tid == 0)
                __hip_atomic_store(gflags + member, 2u * (unsigned)t + 2u,
                                   __ATOMIC_RELAXED, __HIP_MEMORY_SCOPE_AGENT);
            // x@W_{z,r} partials for t+1: overlaps peers' h publishes
            COMPUTE_XA();
        }
    }

    if (tid < 128) {                                   // final output, fp32
        int row = tid >> 3, c4 = tid & 7;
        *(float4*)(out + (size_t)(rowbase + row) * HD + colbase + c4 * 4) =
            *(float4*)&hstate[row][c4 * 4];
    }
}

extern "C" void kernel_launch(void* const* d_in, const int* in_sizes, int n_in,
                              void* d_out, int out_size, void* d_ws, size_t ws_size,
                              hipStream_t stream) {
    const float* x  = (const float*)d_in[0];
    const float* Wz = (const float*)d_in[1];
    const float* Wr = (const float*)d_in[2];
    const float* Wh = (const float*)d_in[3];
    const float* Rz = (const float*)d_in[4];
    const float* Rr = (const float*)d_in[5];
    const float* Rh = (const float*)d_in[6];
    const float* Bz = (const float*)d_in[7];
    const float* Br = (const float*)d_in[8];
    const float* Bh = (const float*)d_in[9];

    char* ws = (char*)d_ws;
    unsigned*       flags = (unsigned*)(ws + FLAGS_OFF);
    unsigned short* WT    = (unsigned short*)(ws + WT_OFF);
    unsigned short* RT    = (unsigned short*)(ws + RT_OFF);
    unsigned short* hbf   = (unsigned short*)(ws + HBF_OFF);
    unsigned short* rhbf  = (unsigned short*)(ws + RH_OFF);

    const bool use_xbf = ws_size >= (size_t)XBF_OFF + XBF_BYTES;
    unsigned short* XBF = use_xbf ? (unsigned short*)(ws + XBF_OFF) : nullptr;

    hipMemsetAsync(ws + FLAGS_OFF, 0, 1024, stream);         // flags = 0
    hipMemsetAsync(ws + HBF_OFF, 0, BB * HD * 2, stream);    // h0 = 0

    dim3 pgrid(HD / 32, HD / 32, 6);
    pack_weights<<<pgrid, 256, 0, stream>>>(Wz, Wr, Wh, Rz, Rr, Rh, WT, RT);
    if (use_xbf)
        pack_x<<<2048, 256, 0, stream>>>(x, XBF,
                                         (long long)((size_t)BB * TT * DIN / 4));

    gru_persistent<<<256, 512, 0, stream>>>(x, XBF, Bz, Br, Bh, WT, RT, hbf, rhbf,
                                            flags, (float*)d_out);
}